// Round 3
// baseline (404.988 us; speedup 1.0000x reference)
//
#include <hip/hip_runtime.h>
#include <math.h>

// ---------------------------------------------------------------------------
// NFM forward, fully-fused split-fp16 MFMA kernel. R3: 512-thr blocks
// (8 waves, 4 waves/SIMD at 2 blocks/CU) + software-pipelined x loads.
//   prep: split/transpose weights into f16 hi/lo planes in d_ws (L2-resident).
//   fused (per 64-row block):
//     FM:  tmp = 0.5*((x@V)^2 + (x^2)@(V^2))  -> LDS hi/lo planes [64][256]
//          lin = x@w_wide + b_wide            -> LDS
//     l1:  h1 = relu(tmp@w1+b1)               -> LDS hi/lo [64][128]
//     l2:  h2 = relu(h1@w2+b2)  (N pad 85->96)-> LDS hi/lo [64][96 in s128]
//     l3:  out = sigmoid(lin + relu(h2@w3+b3)@w_out + b_out)
// LDS: 64 KB activation arena, regions time-multiplexed (see aliases) + small
// lin/partial arrays. XOR-swizzle (16B block b at b^(m&7)) breaks conflicts.
// MFMA = v_mfma_f32_16x16x32_f16, verified layouts:
//   A[m=lane&15][k=(lane>>4)*8+j]; D: col=lane&15, row=(lane>>4)*4+reg.
// ---------------------------------------------------------------------------

typedef _Float16 f16;
typedef _Float16 f16x4 __attribute__((ext_vector_type(4)));
typedef _Float16 f16x8 __attribute__((ext_vector_type(8)));
typedef float f32x4 __attribute__((ext_vector_type(4)));

#define NROWS   131072
#define ROWS    64      // rows per block
#define FDIM    256
#define KDIM    256
#define D1      128
#define D2      85
#define D2P     96

// workspace byte offsets (weights only; ~1.1 MB, L2-resident)
#define OFF_VT_H   0x0UL
#define OFF_VT_L   0x20000UL
#define OFF_V2T    0x40000UL
#define OFF_W1T_H  0x60000UL
#define OFF_W1T_L  0x70000UL
#define OFF_W2T_H  0x80000UL
#define OFF_W2T_L  0x86000UL
#define OFF_W3T_H  0x8C000UL
#define OFF_W3T_L  0x8F000UL

static __device__ __forceinline__ f32x4 mfma16(f16x8 a, f16x8 b, f32x4 c) {
  return __builtin_amdgcn_mfma_f32_16x16x32_f16(a, b, c, 0, 0, 0);
}

// ---------------------------------------------------------------------------
__global__ __launch_bounds__(256) void prep_kernel(
    const float* __restrict__ V, const float* __restrict__ w1,
    const float* __restrict__ w2, const float* __restrict__ w3,
    f16* VT_h, f16* VT_l, f16* V2T,
    f16* W1T_h, f16* W1T_l, f16* W2T_h, f16* W2T_l, f16* W3T_h, f16* W3T_l) {
  int idx0 = blockIdx.x * 256 + threadIdx.x;
  int stride = gridDim.x * 256;
  for (int idx = idx0; idx < KDIM * FDIM; idx += stride) {
    int k = idx >> 8, i = idx & 255;          // VT[k][i] = V[i][k]
    float v = V[i * KDIM + k];
    f16 h = (f16)v;
    VT_h[idx] = h;
    VT_l[idx] = (f16)(v - (float)h);
    V2T[idx] = (f16)(v * v);
  }
  for (int idx = idx0; idx < D1 * KDIM; idx += stride) {
    int n = idx >> 8, k = idx & 255;          // W1T[n][k] = w1[k][n]
    float w = w1[k * D1 + n];
    f16 h = (f16)w;
    W1T_h[idx] = h;
    W1T_l[idx] = (f16)(w - (float)h);
  }
  for (int idx = idx0; idx < D2P * D1; idx += stride) {
    int n = idx >> 7, k = idx & 127;          // W2T[n][k], n>=85 -> 0
    float w = (n < D2) ? w2[k * D2 + n] : 0.f;
    f16 h = (f16)w;
    W2T_h[idx] = h;
    W2T_l[idx] = (f16)(w - (float)h);
  }
  for (int idx = idx0; idx < 64 * D2P; idx += stride) {
    int n = idx / D2P, k = idx - n * D2P;     // W3T[n][k], k>=85 -> 0
    float w = (k < D2) ? w3[k * 64 + n] : 0.f;
    f16 h = (f16)w;
    W3T_h[idx] = h;
    W3T_l[idx] = (f16)(w - (float)h);
  }
}

// ---------------------------------------------------------------------------
__global__ __launch_bounds__(512, 4) void fused_kernel(
    const float* __restrict__ x, const float* __restrict__ w_wide,
    const float* __restrict__ b_wide,
    const f16* __restrict__ VT_h, const f16* __restrict__ VT_l,
    const f16* __restrict__ V2T,
    const f16* __restrict__ W1T_h, const f16* __restrict__ W1T_l,
    const float* __restrict__ b1,
    const f16* __restrict__ W2T_h, const f16* __restrict__ W2T_l,
    const float* __restrict__ b2,
    const f16* __restrict__ W3T_h, const f16* __restrict__ W3T_l,
    const float* __restrict__ b3,
    const float* __restrict__ w_out, const float* __restrict__ b_out,
    float* __restrict__ out) {
  __shared__ __align__(16) f16 smem[32768];  // 64 KB arena
  __shared__ float linS[ROWS];
  __shared__ float pfS[ROWS * 2];

  // region aliases (f16 element offsets); temporally disjoint uses
  f16* tmpH = smem;            // [64][256] swizzled   (FM epi .. l1 loop)
  f16* tmpL = smem + 16384;
  f16* sXh  = smem;            // [64][40] padded      (FM loop only)
  f16* sXl  = smem + 2560;
  f16* sX2  = smem + 5120;
  f16* h1H  = smem + 16384;    // [64][128] swizzled   (l1 epi .. l2 loop)
  f16* h1L  = smem + 24576;
  f16* h2H  = smem;            // [64][96 in stride128] (l2 epi .. l3 loop)
  f16* h2L  = smem + 8192;

  const int tid = threadIdx.x;
  const int lane = tid & 63, wv = tid >> 6;   // wv 0..7
  const int q = lane >> 4, ln = lane & 15;
  const int row0 = blockIdx.x * ROWS;
  const int sr = tid >> 3, sc = (tid & 7) * 4;  // staging: 8 thr/row

  // ---------------- FM stage: wave wv covers n in [wv*32, wv*32+32) --------
  f32x4 accV[4][2], acc2[4][2];
#pragma unroll
  for (int i = 0; i < 4; ++i)
#pragma unroll
    for (int j = 0; j < 2; ++j) {
      accV[i][j] = (f32x4){0.f, 0.f, 0.f, 0.f};
      acc2[i][j] = (f32x4){0.f, 0.f, 0.f, 0.f};
    }
  float linp = 0.f;

  const float* xrow = x + (size_t)(row0 + sr) * FDIM + sc;
  float4 a_cur = *(const float4*)(xrow);
  float4 w_cur = *(const float4*)(w_wide + sc);

  for (int ks = 0; ks < 8; ++ks) {
    const int k0 = ks * 32;
    __syncthreads();  // previous iter's frag reads done before overwrite
    {
      float f0[4] = {a_cur.x, a_cur.y, a_cur.z, a_cur.w};
      f16x4 h0, l0, q0;
#pragma unroll
      for (int j = 0; j < 4; ++j) {
        f16 h = (f16)f0[j];
        h0[j] = h;
        l0[j] = (f16)(f0[j] - (float)h);
        q0[j] = (f16)(f0[j] * f0[j]);
      }
      int off0 = sr * 40 + sc;
      *(f16x4*)(sXh + off0) = h0;
      *(f16x4*)(sXl + off0) = l0;
      *(f16x4*)(sX2 + off0) = q0;
    }
    __syncthreads();

    // software pipeline: issue next iteration's global loads NOW so their
    // HBM latency overlaps this iteration's MFMA section.
    float4 a_nxt = a_cur, w_nxt = w_cur;
    if (ks < 7) {
      a_nxt = *(const float4*)(xrow + k0 + 32);
      w_nxt = *(const float4*)(w_wide + k0 + 32 + sc);
    }
    linp += a_cur.x * w_cur.x + a_cur.y * w_cur.y + a_cur.z * w_cur.z +
            a_cur.w * w_cur.w;

    f16x8 Bh[2], Bl[2], B2[2];
#pragma unroll
    for (int ni = 0; ni < 2; ++ni) {
      int n = wv * 32 + ni * 16 + ln;
      size_t boff = (size_t)n * FDIM + k0 + q * 8;
      Bh[ni] = *(const f16x8*)(VT_h + boff);
      Bl[ni] = *(const f16x8*)(VT_l + boff);
      B2[ni] = *(const f16x8*)(V2T + boff);
    }
#pragma unroll
    for (int mi = 0; mi < 4; ++mi) {
      int off = (mi * 16 + ln) * 40 + q * 8;
      f16x8 Ah = *(const f16x8*)(sXh + off);
      f16x8 Al = *(const f16x8*)(sXl + off);
      f16x8 A2 = *(const f16x8*)(sX2 + off);
#pragma unroll
      for (int ni = 0; ni < 2; ++ni) {
        accV[mi][ni] = mfma16(Al, Bh[ni], accV[mi][ni]);
        accV[mi][ni] = mfma16(Ah, Bl[ni], accV[mi][ni]);
        accV[mi][ni] = mfma16(Ah, Bh[ni], accV[mi][ni]);
        acc2[mi][ni] = mfma16(A2, B2[ni], acc2[mi][ni]);
      }
    }
    a_cur = a_nxt;
    w_cur = w_nxt;
  }

  // wide/linear part -> LDS
  {
    float s0 = linp;
    s0 += __shfl_xor(s0, 1);
    s0 += __shfl_xor(s0, 2);
    s0 += __shfl_xor(s0, 4);
    if ((tid & 7) == 0) linS[sr] = s0 + b_wide[0];
  }

  __syncthreads();  // all frag reads done; staging region may be overwritten

  // FM epilogue: tmp = 0.5*(xv^2 + x2v2) -> LDS hi/lo, swizzled [m][256]
#pragma unroll
  for (int mi = 0; mi < 4; ++mi)
#pragma unroll
    for (int r = 0; r < 4; ++r) {
      int m = mi * 16 + q * 4 + r;
      int mrow = m * 256, msw = m & 7;
#pragma unroll
      for (int ni = 0; ni < 2; ++ni) {
        int n = wv * 32 + ni * 16 + ln;
        float xv = accV[mi][ni][r];
        float val = 0.5f * (xv * xv + acc2[mi][ni][r]);
        f16 hi = (f16)val;
        f16 lo = (f16)(val - (float)hi);
        int off = mrow + (((n >> 3) ^ msw) << 3) + (n & 7);
        tmpH[off] = hi;
        tmpL[off] = lo;
      }
    }

  __syncthreads();

  // ---------------- l1: h1 = relu(tmp@w1+b1), N=128, K=256 -----------------
  // wave wv handles n-tile wv (n = wv*16+ln), all 4 m-tiles
  f32x4 acc1[4];
#pragma unroll
  for (int i = 0; i < 4; ++i) acc1[i] = (f32x4){0.f, 0.f, 0.f, 0.f};

#pragma unroll
  for (int ks = 0; ks < 8; ++ks) {
    size_t boff = (size_t)(wv * 16 + ln) * KDIM + ks * 32 + q * 8;
    f16x8 Bh = *(const f16x8*)(W1T_h + boff);
    f16x8 Bl = *(const f16x8*)(W1T_l + boff);
#pragma unroll
    for (int mi = 0; mi < 4; ++mi) {
      int m = mi * 16 + ln;
      int aoff = m * 256 + (((ks * 4 + q) ^ (m & 7)) << 3);
      f16x8 Ah = *(const f16x8*)(tmpH + aoff);
      f16x8 Al = *(const f16x8*)(tmpL + aoff);
      acc1[mi] = mfma16(Al, Bh, acc1[mi]);
      acc1[mi] = mfma16(Ah, Bl, acc1[mi]);
      acc1[mi] = mfma16(Ah, Bh, acc1[mi]);
    }
  }

  __syncthreads();  // tmp reads done; upper half may be overwritten

  // l1 epilogue -> h1 planes (upper half), swizzled [m][128]
  {
    int n = wv * 16 + ln;
    float bias = b1[n];
#pragma unroll
    for (int mi = 0; mi < 4; ++mi)
#pragma unroll
      for (int r = 0; r < 4; ++r) {
        int m = mi * 16 + q * 4 + r;
        float z = acc1[mi][r] + bias;
        z = z > 0.f ? z : 0.f;
        f16 hi = (f16)z;
        f16 lo = (f16)(z - (float)hi);
        int off = m * 128 + (((n >> 3) ^ (m & 7)) << 3) + (n & 7);
        h1H[off] = hi;
        h1L[off] = lo;
      }
  }

  __syncthreads();

  // ---------------- l2: h2 = relu(h1@w2+b2), N=96(pad), K=128 --------------
  // wave (mt = wv&3, half = wv>>2): rows mt*16..+15, n-tiles half*3..half*3+2
  const int mt = wv & 3, half = wv >> 2;
  f32x4 accL2[3];
#pragma unroll
  for (int j = 0; j < 3; ++j) accL2[j] = (f32x4){0.f, 0.f, 0.f, 0.f};

#pragma unroll
  for (int ks = 0; ks < 4; ++ks) {
    int m = mt * 16 + ln;
    int aoff = m * 128 + (((ks * 4 + q) ^ (m & 7)) << 3);
    f16x8 Ah = *(const f16x8*)(h1H + aoff);
    f16x8 Al = *(const f16x8*)(h1L + aoff);
#pragma unroll
    for (int nj = 0; nj < 3; ++nj) {
      int n = (half * 3 + nj) * 16 + ln;
      size_t boff = (size_t)n * D1 + ks * 32 + q * 8;
      f16x8 Bh = *(const f16x8*)(W2T_h + boff);
      f16x8 Bl = *(const f16x8*)(W2T_l + boff);
      accL2[nj] = mfma16(Al, Bh, accL2[nj]);
      accL2[nj] = mfma16(Ah, Bl, accL2[nj]);
      accL2[nj] = mfma16(Ah, Bh, accL2[nj]);
    }
  }

  // l2 epilogue -> h2 planes (lower region, disjoint from h1): no barrier
#pragma unroll
  for (int r = 0; r < 4; ++r) {
    int m = mt * 16 + q * 4 + r;
    int mrow = m * 128, msw = m & 7;
#pragma unroll
    for (int nj = 0; nj < 3; ++nj) {
      int n = (half * 3 + nj) * 16 + ln;
      float z = accL2[nj][r] + ((n < D2) ? b2[n] : 0.f);
      z = z > 0.f ? z : 0.f;
      f16 hi = (f16)z;
      f16 lo = (f16)(z - (float)hi);
      int off = mrow + (((n >> 3) ^ msw) << 3) + (n & 7);
      h2H[off] = hi;
      h2L[off] = lo;
    }
  }

  __syncthreads();

  // ---------------- l3 + out: K=96, N=64 ----------------
  // wave (mt, half): rows mt*16..+15, n-tiles half*2, half*2+1
  f32x4 accL3[2];
  accL3[0] = (f32x4){0.f, 0.f, 0.f, 0.f};
  accL3[1] = (f32x4){0.f, 0.f, 0.f, 0.f};

#pragma unroll
  for (int ks = 0; ks < 3; ++ks) {
    int m = mt * 16 + ln;
    int aoff = m * 128 + (((ks * 4 + q) ^ (m & 7)) << 3);
    f16x8 Ah = *(const f16x8*)(h2H + aoff);
    f16x8 Al = *(const f16x8*)(h2L + aoff);
#pragma unroll
    for (int nj = 0; nj < 2; ++nj) {
      int n = (half * 2 + nj) * 16 + ln;
      size_t boff = (size_t)n * D2P + ks * 32 + q * 8;
      f16x8 Bh = *(const f16x8*)(W3T_h + boff);
      f16x8 Bl = *(const f16x8*)(W3T_l + boff);
      accL3[nj] = mfma16(Al, Bh, accL3[nj]);
      accL3[nj] = mfma16(Ah, Bl, accL3[nj]);
      accL3[nj] = mfma16(Ah, Bh, accL3[nj]);
    }
  }

  {
    float b3v[2], wov[2];
#pragma unroll
    for (int nj = 0; nj < 2; ++nj) {
      int n = (half * 2 + nj) * 16 + ln;
      b3v[nj] = b3[n];
      wov[nj] = w_out[n];
    }
#pragma unroll
    for (int r = 0; r < 4; ++r) {
      float part = 0.f;
#pragma unroll
      for (int nj = 0; nj < 2; ++nj) {
        float z = accL3[nj][r] + b3v[nj];
        part += (z > 0.f ? z : 0.f) * wov[nj];
      }
      part += __shfl_xor(part, 1);
      part += __shfl_xor(part, 2);
      part += __shfl_xor(part, 4);
      part += __shfl_xor(part, 8);
      if (ln == 0) pfS[(mt * 16 + q * 4 + r) * 2 + half] = part;
    }
  }

  __syncthreads();

  if (tid < ROWS) {
    float zf = linS[tid] + pfS[tid * 2] + pfS[tid * 2 + 1] + b_out[0];
    out[row0 + tid] = 1.f / (1.f + expf(-zf));
  }
}

// ---------------------------------------------------------------------------
extern "C" void kernel_launch(void* const* d_in, const int* in_sizes, int n_in,
                              void* d_out, int out_size, void* d_ws, size_t ws_size,
                              hipStream_t stream) {
  const float* x = (const float*)d_in[0];
  const float* w_wide = (const float*)d_in[1];
  const float* b_wide = (const float*)d_in[2];
  const float* V = (const float*)d_in[3];
  const float* w1 = (const float*)d_in[4];
  const float* b1 = (const float*)d_in[5];
  const float* w2 = (const float*)d_in[6];
  const float* b2 = (const float*)d_in[7];
  const float* w3 = (const float*)d_in[8];
  const float* b3 = (const float*)d_in[9];
  const float* w_out = (const float*)d_in[10];
  const float* b_out = (const float*)d_in[11];
  float* out = (float*)d_out;
  char* ws = (char*)d_ws;

  f16* VT_h = (f16*)(ws + OFF_VT_H);
  f16* VT_l = (f16*)(ws + OFF_VT_L);
  f16* V2T = (f16*)(ws + OFF_V2T);
  f16* W1T_h = (f16*)(ws + OFF_W1T_H);
  f16* W1T_l = (f16*)(ws + OFF_W1T_L);
  f16* W2T_h = (f16*)(ws + OFF_W2T_H);
  f16* W2T_l = (f16*)(ws + OFF_W2T_L);
  f16* W3T_h = (f16*)(ws + OFF_W3T_H);
  f16* W3T_l = (f16*)(ws + OFF_W3T_L);

  prep_kernel<<<64, 256, 0, stream>>>(V, w1, w2, w3, VT_h, VT_l, V2T, W1T_h,
                                      W1T_l, W2T_h, W2T_l, W3T_h, W3T_l);

  fused_kernel<<<NROWS / ROWS, 512, 0, stream>>>(
      x, w_wide, b_wide, VT_h, VT_l, V2T, W1T_h, W1T_l, b1, W2T_h, W2T_l, b2,
      W3T_h, W3T_l, b3, w_out, b_out, out);
}

// Round 4
// 398.022 us; speedup vs baseline: 1.0175x; 1.0175x over previous
//
#include <hip/hip_runtime.h>
#include <math.h>

// ---------------------------------------------------------------------------
// NFM forward, fully-fused split-fp16 MFMA kernel. R4: despill at 4 waves/SIMD.
//   - 512-thr blocks, __launch_bounds__(512,4): 128 unified regs/wave, and the
//     kernel is restructured to actually fit (no prefetch pipeline; B-frags 24
//     + A-frags 12 + acc 64 AGPR ~= 109).
//   - FM K-loop staged in 2 chunks of 128 (pad-136 LDS planes, 52KB transient)
//     -> 5 barriers in FM instead of 16 (fewer vmcnt(0) drains).
// Stages per 64-row block:
//   FM:  tmp = 0.5*((x@V)^2 + (x^2)@(V^2))  [split-f16 xv ×3 + plain-f16 sq]
//        lin = x@w_wide + b_wide            -> LDS
//   l1:  h1 = relu(tmp@w1+b1)  [split]      -> LDS
//   l2:  h2 = relu(h1@w2+b2)   [split, N pad 85->96]
//   l3:  out = sigmoid(lin + relu(h2@w3+b3)@w_out + b_out)
// LDS: 64KB arena time-multiplexed; XOR-swizzle on activation planes.
// MFMA = v_mfma_f32_16x16x32_f16, verified layouts:
//   A[m=lane&15][k=(lane>>4)*8+j]; D: col=lane&15, row=(lane>>4)*4+reg.
// ---------------------------------------------------------------------------

typedef _Float16 f16;
typedef _Float16 f16x4 __attribute__((ext_vector_type(4)));
typedef _Float16 f16x8 __attribute__((ext_vector_type(8)));
typedef float f32x4 __attribute__((ext_vector_type(4)));

#define NROWS   131072
#define ROWS    64
#define FDIM    256
#define KDIM    256
#define D1      128
#define D2      85
#define D2P     96

#define SSTRIDE 136   // staging plane stride (128 + 8 pad)

// workspace byte offsets (weights only; ~1.1 MB, L2-resident)
#define OFF_VT_H   0x0UL
#define OFF_VT_L   0x20000UL
#define OFF_V2T    0x40000UL
#define OFF_W1T_H  0x60000UL
#define OFF_W1T_L  0x70000UL
#define OFF_W2T_H  0x80000UL
#define OFF_W2T_L  0x86000UL
#define OFF_W3T_H  0x8C000UL
#define OFF_W3T_L  0x8F000UL

static __device__ __forceinline__ f32x4 mfma16(f16x8 a, f16x8 b, f32x4 c) {
  return __builtin_amdgcn_mfma_f32_16x16x32_f16(a, b, c, 0, 0, 0);
}

// ---------------------------------------------------------------------------
__global__ __launch_bounds__(256) void prep_kernel(
    const float* __restrict__ V, const float* __restrict__ w1,
    const float* __restrict__ w2, const float* __restrict__ w3,
    f16* VT_h, f16* VT_l, f16* V2T,
    f16* W1T_h, f16* W1T_l, f16* W2T_h, f16* W2T_l, f16* W3T_h, f16* W3T_l) {
  int idx0 = blockIdx.x * 256 + threadIdx.x;
  int stride = gridDim.x * 256;
  for (int idx = idx0; idx < KDIM * FDIM; idx += stride) {
    int k = idx >> 8, i = idx & 255;          // VT[k][i] = V[i][k]
    float v = V[i * KDIM + k];
    f16 h = (f16)v;
    VT_h[idx] = h;
    VT_l[idx] = (f16)(v - (float)h);
    V2T[idx] = (f16)(v * v);
  }
  for (int idx = idx0; idx < D1 * KDIM; idx += stride) {
    int n = idx >> 8, k = idx & 255;          // W1T[n][k] = w1[k][n]
    float w = w1[k * D1 + n];
    f16 h = (f16)w;
    W1T_h[idx] = h;
    W1T_l[idx] = (f16)(w - (float)h);
  }
  for (int idx = idx0; idx < D2P * D1; idx += stride) {
    int n = idx >> 7, k = idx & 127;          // W2T[n][k], n>=85 -> 0
    float w = (n < D2) ? w2[k * D2 + n] : 0.f;
    f16 h = (f16)w;
    W2T_h[idx] = h;
    W2T_l[idx] = (f16)(w - (float)h);
  }
  for (int idx = idx0; idx < 64 * D2P; idx += stride) {
    int n = idx / D2P, k = idx - n * D2P;     // W3T[n][k], k>=85 -> 0
    float w = (k < D2) ? w3[k * 64 + n] : 0.f;
    f16 h = (f16)w;
    W3T_h[idx] = h;
    W3T_l[idx] = (f16)(w - (float)h);
  }
}

// ---------------------------------------------------------------------------
__global__ __launch_bounds__(512, 4) void fused_kernel(
    const float* __restrict__ x, const float* __restrict__ w_wide,
    const float* __restrict__ b_wide,
    const f16* __restrict__ VT_h, const f16* __restrict__ VT_l,
    const f16* __restrict__ V2T,
    const f16* __restrict__ W1T_h, const f16* __restrict__ W1T_l,
    const float* __restrict__ b1,
    const f16* __restrict__ W2T_h, const f16* __restrict__ W2T_l,
    const float* __restrict__ b2,
    const f16* __restrict__ W3T_h, const f16* __restrict__ W3T_l,
    const float* __restrict__ b3,
    const float* __restrict__ w_out, const float* __restrict__ b_out,
    float* __restrict__ out) {
  __shared__ __align__(16) f16 smem[32768];  // 64 KB arena
  __shared__ float linS[ROWS];
  __shared__ float pfS[ROWS * 2];

  // region aliases (f16 element offsets); temporally disjoint uses
  f16* sXh  = smem;            // [64][136] pad        (FM loop only, 52KB w/ 3)
  f16* sXl  = smem + 8704;
  f16* sX2  = smem + 17408;
  f16* tmpH = smem;            // [64][256] swizzled   (FM epi .. l1 loop)
  f16* tmpL = smem + 16384;
  f16* h1H  = smem + 16384;    // [64][128] swizzled   (l1 epi .. l2 loop)
  f16* h1L  = smem + 24576;
  f16* h2H  = smem;            // [64][96 in s128]     (l2 epi .. l3 loop)
  f16* h2L  = smem + 8192;

  const int tid = threadIdx.x;
  const int lane = tid & 63, wv = tid >> 6;   // wv 0..7
  const int q = lane >> 4, ln = lane & 15;
  const int row0 = blockIdx.x * ROWS;
  const int sr = tid >> 3, sc = (tid & 7) * 16;  // staging: 8 thr/row, 16 f32

  // ---------------- FM stage: wave wv covers n in [wv*32, wv*32+32) --------
  f32x4 accV[4][2], acc2[4][2];
#pragma unroll
  for (int i = 0; i < 4; ++i)
#pragma unroll
    for (int j = 0; j < 2; ++j) {
      accV[i][j] = (f32x4){0.f, 0.f, 0.f, 0.f};
      acc2[i][j] = (f32x4){0.f, 0.f, 0.f, 0.f};
    }
  float linp = 0.f;

  for (int kk = 0; kk < 2; ++kk) {
    const int kbase = kk * 128;
    // issue this chunk's global loads BEFORE the barrier (latency overlaps
    // other waves' previous-chunk MFMAs + barrier wait)
    float4 a[4], w4[4];
    const float* xp = x + (size_t)(row0 + sr) * FDIM + kbase + sc;
    const float* wp = w_wide + kbase + sc;
#pragma unroll
    for (int t = 0; t < 4; ++t) {
      a[t] = *(const float4*)(xp + t * 4);
      w4[t] = *(const float4*)(wp + t * 4);
    }
    __syncthreads();  // previous chunk's frag reads done before overwrite
#pragma unroll
    for (int t = 0; t < 4; ++t) {
      linp += a[t].x * w4[t].x + a[t].y * w4[t].y + a[t].z * w4[t].z +
              a[t].w * w4[t].w;
      float f0[4] = {a[t].x, a[t].y, a[t].z, a[t].w};
      f16x4 h0, l0, q0;
#pragma unroll
      for (int j = 0; j < 4; ++j) {
        f16 h = (f16)f0[j];
        h0[j] = h;
        l0[j] = (f16)(f0[j] - (float)h);
        q0[j] = (f16)(f0[j] * f0[j]);
      }
      int off0 = sr * SSTRIDE + sc + t * 4;
      *(f16x4*)(sXh + off0) = h0;
      *(f16x4*)(sXl + off0) = l0;
      *(f16x4*)(sX2 + off0) = q0;
    }
    __syncthreads();

#pragma unroll
    for (int ks = 0; ks < 4; ++ks) {
      const int k0 = kbase + ks * 32;
      f16x8 Bh[2], Bl[2], B2[2];
#pragma unroll
      for (int ni = 0; ni < 2; ++ni) {
        int n = wv * 32 + ni * 16 + ln;
        size_t boff = (size_t)n * FDIM + k0 + q * 8;
        Bh[ni] = *(const f16x8*)(VT_h + boff);
        Bl[ni] = *(const f16x8*)(VT_l + boff);
        B2[ni] = *(const f16x8*)(V2T + boff);
      }
#pragma unroll
      for (int mi = 0; mi < 4; ++mi) {
        int aoff = (mi * 16 + ln) * SSTRIDE + ks * 32 + q * 8;
        f16x8 Ah = *(const f16x8*)(sXh + aoff);
        f16x8 Al = *(const f16x8*)(sXl + aoff);
        f16x8 A2 = *(const f16x8*)(sX2 + aoff);
#pragma unroll
        for (int ni = 0; ni < 2; ++ni) {
          accV[mi][ni] = mfma16(Al, Bh[ni], accV[mi][ni]);
          accV[mi][ni] = mfma16(Ah, Bl[ni], accV[mi][ni]);
          accV[mi][ni] = mfma16(Ah, Bh[ni], accV[mi][ni]);
          acc2[mi][ni] = mfma16(A2, B2[ni], acc2[mi][ni]);
        }
      }
    }
  }

  // wide/linear part -> LDS
  {
    float s0 = linp;
    s0 += __shfl_xor(s0, 1);
    s0 += __shfl_xor(s0, 2);
    s0 += __shfl_xor(s0, 4);
    if ((tid & 7) == 0) linS[sr] = s0 + b_wide[0];
  }

  __syncthreads();  // all frag reads done; staging region may be overwritten

  // FM epilogue: tmp = 0.5*(xv^2 + x2v2) -> LDS hi/lo, swizzled [m][256]
#pragma unroll
  for (int mi = 0; mi < 4; ++mi)
#pragma unroll
    for (int r = 0; r < 4; ++r) {
      int m = mi * 16 + q * 4 + r;
      int mrow = m * 256, msw = m & 7;
#pragma unroll
      for (int ni = 0; ni < 2; ++ni) {
        int n = wv * 32 + ni * 16 + ln;
        float xv = accV[mi][ni][r];
        float val = 0.5f * (xv * xv + acc2[mi][ni][r]);
        f16 hi = (f16)val;
        f16 lo = (f16)(val - (float)hi);
        int off = mrow + (((n >> 3) ^ msw) << 3) + (n & 7);
        tmpH[off] = hi;
        tmpL[off] = lo;
      }
    }

  __syncthreads();

  // ---------------- l1: h1 = relu(tmp@w1+b1), N=128, K=256 -----------------
  // wave wv handles n-tile wv (n = wv*16+ln), all 4 m-tiles
  f32x4 acc1[4];
#pragma unroll
  for (int i = 0; i < 4; ++i) acc1[i] = (f32x4){0.f, 0.f, 0.f, 0.f};

#pragma unroll
  for (int ks = 0; ks < 8; ++ks) {
    size_t boff = (size_t)(wv * 16 + ln) * KDIM + ks * 32 + q * 8;
    f16x8 Bh = *(const f16x8*)(W1T_h + boff);
    f16x8 Bl = *(const f16x8*)(W1T_l + boff);
#pragma unroll
    for (int mi = 0; mi < 4; ++mi) {
      int m = mi * 16 + ln;
      int aoff = m * 256 + (((ks * 4 + q) ^ (m & 7)) << 3);
      f16x8 Ah = *(const f16x8*)(tmpH + aoff);
      f16x8 Al = *(const f16x8*)(tmpL + aoff);
      acc1[mi] = mfma16(Al, Bh, acc1[mi]);
      acc1[mi] = mfma16(Ah, Bl, acc1[mi]);
      acc1[mi] = mfma16(Ah, Bh, acc1[mi]);
    }
  }

  __syncthreads();  // tmp reads done; upper half may be overwritten

  // l1 epilogue -> h1 planes (upper half), swizzled [m][128]
  {
    int n = wv * 16 + ln;
    float bias = b1[n];
#pragma unroll
    for (int mi = 0; mi < 4; ++mi)
#pragma unroll
      for (int r = 0; r < 4; ++r) {
        int m = mi * 16 + q * 4 + r;
        float z = acc1[mi][r] + bias;
        z = z > 0.f ? z : 0.f;
        f16 hi = (f16)z;
        f16 lo = (f16)(z - (float)hi);
        int off = m * 128 + (((n >> 3) ^ (m & 7)) << 3) + (n & 7);
        h1H[off] = hi;
        h1L[off] = lo;
      }
  }

  __syncthreads();

  // ---------------- l2: h2 = relu(h1@w2+b2), N=96(pad), K=128 --------------
  // wave (mt = wv&3, half = wv>>2): rows mt*16..+15, n-tiles half*3..half*3+2
  const int mt = wv & 3, half = wv >> 2;
  f32x4 accL2[3];
#pragma unroll
  for (int j = 0; j < 3; ++j) accL2[j] = (f32x4){0.f, 0.f, 0.f, 0.f};

#pragma unroll
  for (int ks = 0; ks < 4; ++ks) {
    int m = mt * 16 + ln;
    int aoff = m * 128 + (((ks * 4 + q) ^ (m & 7)) << 3);
    f16x8 Ah = *(const f16x8*)(h1H + aoff);
    f16x8 Al = *(const f16x8*)(h1L + aoff);
#pragma unroll
    for (int nj = 0; nj < 3; ++nj) {
      int n = (half * 3 + nj) * 16 + ln;
      size_t boff = (size_t)n * D1 + ks * 32 + q * 8;
      f16x8 Bh = *(const f16x8*)(W2T_h + boff);
      f16x8 Bl = *(const f16x8*)(W2T_l + boff);
      accL2[nj] = mfma16(Al, Bh, accL2[nj]);
      accL2[nj] = mfma16(Ah, Bl, accL2[nj]);
      accL2[nj] = mfma16(Ah, Bh, accL2[nj]);
    }
  }

  // l2 epilogue -> h2 planes (lower region, disjoint from h1): no barrier
#pragma unroll
  for (int r = 0; r < 4; ++r) {
    int m = mt * 16 + q * 4 + r;
    int mrow = m * 128, msw = m & 7;
#pragma unroll
    for (int nj = 0; nj < 3; ++nj) {
      int n = (half * 3 + nj) * 16 + ln;
      float z = accL2[nj][r] + ((n < D2) ? b2[n] : 0.f);
      z = z > 0.f ? z : 0.f;
      f16 hi = (f16)z;
      f16 lo = (f16)(z - (float)hi);
      int off = mrow + (((n >> 3) ^ msw) << 3) + (n & 7);
      h2H[off] = hi;
      h2L[off] = lo;
    }
  }

  __syncthreads();

  // ---------------- l3 + out: K=96, N=64 ----------------
  // wave (mt, half): rows mt*16..+15, n-tiles half*2, half*2+1
  f32x4 accL3[2];
  accL3[0] = (f32x4){0.f, 0.f, 0.f, 0.f};
  accL3[1] = (f32x4){0.f, 0.f, 0.f, 0.f};

#pragma unroll
  for (int ks = 0; ks < 3; ++ks) {
    int m = mt * 16 + ln;
    int aoff = m * 128 + (((ks * 4 + q) ^ (m & 7)) << 3);
    f16x8 Ah = *(const f16x8*)(h2H + aoff);
    f16x8 Al = *(const f16x8*)(h2L + aoff);
#pragma unroll
    for (int nj = 0; nj < 2; ++nj) {
      int n = (half * 2 + nj) * 16 + ln;
      size_t boff = (size_t)n * D2P + ks * 32 + q * 8;
      f16x8 Bh = *(const f16x8*)(W3T_h + boff);
      f16x8 Bl = *(const f16x8*)(W3T_l + boff);
      accL3[nj] = mfma16(Al, Bh, accL3[nj]);
      accL3[nj] = mfma16(Ah, Bl, accL3[nj]);
      accL3[nj] = mfma16(Ah, Bh, accL3[nj]);
    }
  }

  {
    float b3v[2], wov[2];
#pragma unroll
    for (int nj = 0; nj < 2; ++nj) {
      int n = (half * 2 + nj) * 16 + ln;
      b3v[nj] = b3[n];
      wov[nj] = w_out[n];
    }
#pragma unroll
    for (int r = 0; r < 4; ++r) {
      float part = 0.f;
#pragma unroll
      for (int nj = 0; nj < 2; ++nj) {
        float z = accL3[nj][r] + b3v[nj];
        part += (z > 0.f ? z : 0.f) * wov[nj];
      }
      part += __shfl_xor(part, 1);
      part += __shfl_xor(part, 2);
      part += __shfl_xor(part, 4);
      part += __shfl_xor(part, 8);
      if (ln == 0) pfS[(mt * 16 + q * 4 + r) * 2 + half] = part;
    }
  }

  __syncthreads();

  if (tid < ROWS) {
    float zf = linS[tid] + pfS[tid * 2] + pfS[tid * 2 + 1] + b_out[0];
    out[row0 + tid] = 1.f / (1.f + expf(-zf));
  }
}

// ---------------------------------------------------------------------------
extern "C" void kernel_launch(void* const* d_in, const int* in_sizes, int n_in,
                              void* d_out, int out_size, void* d_ws, size_t ws_size,
                              hipStream_t stream) {
  const float* x = (const float*)d_in[0];
  const float* w_wide = (const float*)d_in[1];
  const float* b_wide = (const float*)d_in[2];
  const float* V = (const float*)d_in[3];
  const float* w1 = (const float*)d_in[4];
  const float* b1 = (const float*)d_in[5];
  const float* w2 = (const float*)d_in[6];
  const float* b2 = (const float*)d_in[7];
  const float* w3 = (const float*)d_in[8];
  const float* b3 = (const float*)d_in[9];
  const float* w_out = (const float*)d_in[10];
  const float* b_out = (const float*)d_in[11];
  float* out = (float*)d_out;
  char* ws = (char*)d_ws;

  f16* VT_h = (f16*)(ws + OFF_VT_H);
  f16* VT_l = (f16*)(ws + OFF_VT_L);
  f16* V2T = (f16*)(ws + OFF_V2T);
  f16* W1T_h = (f16*)(ws + OFF_W1T_H);
  f16* W1T_l = (f16*)(ws + OFF_W1T_L);
  f16* W2T_h = (f16*)(ws + OFF_W2T_H);
  f16* W2T_l = (f16*)(ws + OFF_W2T_L);
  f16* W3T_h = (f16*)(ws + OFF_W3T_H);
  f16* W3T_l = (f16*)(ws + OFF_W3T_L);

  prep_kernel<<<64, 256, 0, stream>>>(V, w1, w2, w3, VT_h, VT_l, V2T, W1T_h,
                                      W1T_l, W2T_h, W2T_l, W3T_h, W3T_l);

  fused_kernel<<<NROWS / ROWS, 512, 0, stream>>>(
      x, w_wide, b_wide, VT_h, VT_l, V2T, W1T_h, W1T_l, b1, W2T_h, W2T_l, b2,
      W3T_h, W3T_l, b3, w_out, b_out, out);
}